// Round 1
// baseline (269.864 us; speedup 1.0000x reference)
//
#include <hip/hip_runtime.h>
#include <hip/hip_bf16.h>
#include <stdint.h>

#define HIDDEN 1024
#define SEQ 2048
#define BATCH 2
#define HEADS 16
#define HDIM 64
#define M_TOK (BATCH * SEQ)  // 4096

using bf16_t = __bf16;
typedef __attribute__((ext_vector_type(8))) __bf16 bf16x8;
typedef __attribute__((ext_vector_type(4))) float f32x4;

__device__ __forceinline__ bf16_t tobf(float f) {
  uint32_t u = __builtin_bit_cast(uint32_t, f);
  u += 0x7FFFu + ((u >> 16) & 1u);  // round-to-nearest-even
  uint16_t h = (uint16_t)(u >> 16);
  return __builtin_bit_cast(bf16_t, h);
}

__device__ __forceinline__ void async_cp16(const bf16_t* g, bf16_t* l) {
  __builtin_amdgcn_global_load_lds(
      (const __attribute__((address_space(1))) uint32_t*)g,
      (__attribute__((address_space(3))) uint32_t*)l, 16, 0, 0);
}

// ---------------- fp32 -> bf16 convert ----------------
__global__ __launch_bounds__(256) void k_convert(const float* __restrict__ src,
                                                 bf16_t* __restrict__ dst, int n) {
  int i = (blockIdx.x * 256 + threadIdx.x) * 4;
  if (i >= n) return;
  float4 v = *(const float4*)(src + i);
  union { bf16_t b[4]; uint64_t u; } o;
  o.b[0] = tobf(v.x); o.b[1] = tobf(v.y); o.b[2] = tobf(v.z); o.b[3] = tobf(v.w);
  *(uint64_t*)(dst + i) = o.u;
}

// ---------------- GEMM: C[m,n] = sum_k A[m,k] * Bw[n,k] + bias[n] ----------------
// MODE 0: bf16 out scattered to [B][H][S][D]   MODE 1: f32 out linear [M][N]
template <int MODE>
__global__ __launch_bounds__(256) void k_gemm_bt(const bf16_t* __restrict__ A,
                                                 const bf16_t* __restrict__ Bw,
                                                 const float* __restrict__ bias,
                                                 void* __restrict__ dst) {
  constexpr int K = HIDDEN;
  __shared__ bf16_t As[128 * 32];
  __shared__ bf16_t Bs[128 * 32];
  const int tid = threadIdx.x;
  const int lane = tid & 63;
  const int w = tid >> 6;
  const int wr = w >> 1, wc = w & 1;
  const int lr = lane & 15, lg = lane >> 4;
  const int m0 = blockIdx.x * 128;
  const int n0 = blockIdx.y * 128;

  f32x4 acc[4][4];
#pragma unroll
  for (int i = 0; i < 4; ++i)
#pragma unroll
    for (int j = 0; j < 4; ++j) acc[i][j] = f32x4{0.f, 0.f, 0.f, 0.f};

  for (int k0 = 0; k0 < K; k0 += 32) {
#pragma unroll
    for (int i = 0; i < 2; ++i) {
      int c = w * 128 + i * 64 + lane;  // 0..511, 16B chunk id
      int row = c >> 2, kc = c & 3;
      async_cp16(A + (size_t)(m0 + row) * K + k0 + kc * 8, As + c * 8);
      async_cp16(Bw + (size_t)(n0 + row) * K + k0 + kc * 8, Bs + c * 8);
    }
    __syncthreads();
    bf16x8 af[4], bfr[4];
#pragma unroll
    for (int mi = 0; mi < 4; ++mi)
      af[mi] = *(const bf16x8*)(As + (wr * 64 + mi * 16 + lr) * 32 + lg * 8);
#pragma unroll
    for (int ni = 0; ni < 4; ++ni)
      bfr[ni] = *(const bf16x8*)(Bs + (wc * 64 + ni * 16 + lr) * 32 + lg * 8);
#pragma unroll
    for (int mi = 0; mi < 4; ++mi)
#pragma unroll
      for (int ni = 0; ni < 4; ++ni)
        acc[mi][ni] = __builtin_amdgcn_mfma_f32_16x16x32_bf16(af[mi], bfr[ni], acc[mi][ni], 0, 0, 0);
    __syncthreads();
  }

#pragma unroll
  for (int ni = 0; ni < 4; ++ni) {
    int col = n0 + wc * 64 + ni * 16 + lr;
    float bv = bias[col];
#pragma unroll
    for (int mi = 0; mi < 4; ++mi) {
#pragma unroll
      for (int r = 0; r < 4; ++r) {
        int m = m0 + wr * 64 + mi * 16 + lg * 4 + r;
        float v = acc[mi][ni][r] + bv;
        if (MODE == 0) {
          int b = m >> 11, s = m & (SEQ - 1);
          int h = col >> 6, d = col & 63;
          ((bf16_t*)dst)[(((size_t)(b * HEADS + h) * SEQ) + s) * HDIM + d] = tobf(v);
        } else {
          ((float*)dst)[(size_t)m * HIDDEN + col] = v;
        }
      }
    }
  }
}

// ---------------- flash attention ----------------
// grid: (SEQ/64, BATCH*HEADS), block 256. Wave w handles q-rows [q0, q0+16).
__global__ __launch_bounds__(256) void k_attn(const bf16_t* __restrict__ Q,
                                              const bf16_t* __restrict__ Kk,
                                              const bf16_t* __restrict__ V,
                                              bf16_t* __restrict__ AO) {
  __shared__ bf16_t Vt[64 * 64];      // transposed V tile [d][k], XOR-swizzled
  __shared__ bf16_t Pl[4][16 * 64];   // per-wave P tile, XOR-swizzled
  const int tid = threadIdx.x;
  const int lane = tid & 63;
  const int w = tid >> 6;
  const int lr = lane & 15, lg = lane >> 4;
  const int bh = blockIdx.y;
  const int q0 = blockIdx.x * 64 + w * 16;
  const bf16_t* Qh = Q + (size_t)bh * SEQ * HDIM;
  const bf16_t* Kh = Kk + (size_t)bh * SEQ * HDIM;
  const bf16_t* Vh = V + (size_t)bh * SEQ * HDIM;

  // Q fragments, scale folded in (1/sqrt(64) * log2(e) so we can use exp2)
  const float qscale = 0.125f * 1.44269504088896f;
  bf16x8 aq[2];
#pragma unroll
  for (int dc = 0; dc < 2; ++dc) {
    bf16x8 t = *(const bf16x8*)(Qh + (size_t)(q0 + lr) * HDIM + dc * 32 + lg * 8);
#pragma unroll
    for (int j = 0; j < 8; ++j) t[j] = tobf((float)t[j] * qscale);
    aq[dc] = t;
  }

  float mrow[4], lsum[4];
  f32x4 acc[4];
#pragma unroll
  for (int r = 0; r < 4; ++r) { mrow[r] = -1e30f; lsum[r] = 0.f; }
#pragma unroll
  for (int fc = 0; fc < 4; ++fc) acc[fc] = f32x4{0.f, 0.f, 0.f, 0.f};

  for (int kt = 0; kt < SEQ / 64; ++kt) {
    const int kr0 = kt * 64;
    __syncthreads();  // protect Vt from overwrite while still being read
    {   // stage V tile transposed + swizzled: thread -> (k = tid>>2, d0 = (tid&3)*16)
      int k = tid >> 2, d0 = (tid & 3) * 16;
      const bf16_t* vp = Vh + (size_t)(kr0 + k) * HDIM + d0;
#pragma unroll
      for (int half = 0; half < 2; ++half) {
        bf16x8 vv = *(const bf16x8*)(vp + half * 8);
#pragma unroll
        for (int j = 0; j < 8; ++j) {
          int d = d0 + half * 8 + j;
          Vt[d * 64 + (((k >> 3) ^ (d & 7)) * 8) + (k & 7)] = vv[j];
        }
      }
    }
    __syncthreads();

    // S = Q @ K^T  (K fragments straight from global; tile is L2-resident)
    f32x4 sf[4];
#pragma unroll
    for (int fc = 0; fc < 4; ++fc) {
      f32x4 a = f32x4{0.f, 0.f, 0.f, 0.f};
      int kr = kr0 + fc * 16 + lr;
#pragma unroll
      for (int dc = 0; dc < 2; ++dc) {
        bf16x8 bk = *(const bf16x8*)(Kh + (size_t)kr * HDIM + dc * 32 + lg * 8);
        a = __builtin_amdgcn_mfma_f32_16x16x32_bf16(aq[dc], bk, a, 0, 0, 0);
      }
      sf[fc] = a;
    }

    // online softmax (exp2 domain); lane owns rows lg*4+r, cols fc*16+lr
    float pv[4][4];
#pragma unroll
    for (int r = 0; r < 4; ++r) {
      float mx = fmaxf(fmaxf(sf[0][r], sf[1][r]), fmaxf(sf[2][r], sf[3][r]));
      mx = fmaxf(mx, __shfl_xor(mx, 1));
      mx = fmaxf(mx, __shfl_xor(mx, 2));
      mx = fmaxf(mx, __shfl_xor(mx, 4));
      mx = fmaxf(mx, __shfl_xor(mx, 8));
      float mn = fmaxf(mrow[r], mx);
      float sc = exp2f(mrow[r] - mn);
      mrow[r] = mn;
      float ts = 0.f;
#pragma unroll
      for (int fc = 0; fc < 4; ++fc) {
        float p = exp2f(sf[fc][r] - mn);
        pv[fc][r] = p;
        ts += p;
      }
      ts += __shfl_xor(ts, 1);
      ts += __shfl_xor(ts, 2);
      ts += __shfl_xor(ts, 4);
      ts += __shfl_xor(ts, 8);
      lsum[r] = lsum[r] * sc + ts;
#pragma unroll
      for (int fc = 0; fc < 4; ++fc) acc[fc][r] = acc[fc][r] * sc;
    }

    // P -> LDS (swizzled), wave-private
#pragma unroll
    for (int fc = 0; fc < 4; ++fc) {
      int col = fc * 16 + lr;
#pragma unroll
      for (int r = 0; r < 4; ++r) {
        int row = lg * 4 + r;
        Pl[w][row * 64 + (((col >> 3) ^ (row & 7)) * 8) + (col & 7)] = tobf(pv[fc][r]);
      }
    }

    // P A-fragments back from LDS
    bf16x8 pa[2];
#pragma unroll
    for (int kc = 0; kc < 2; ++kc) {
      int swz = (kc * 4 + lg) ^ (lr & 7);
      pa[kc] = *(const bf16x8*)(&Pl[w][lr * 64 + swz * 8]);
    }
    // O += P @ V
#pragma unroll
    for (int fc = 0; fc < 4; ++fc) {
      int d = fc * 16 + lr;
#pragma unroll
      for (int kc = 0; kc < 2; ++kc) {
        int swz = (kc * 4 + lg) ^ (d & 7);
        bf16x8 bv = *(const bf16x8*)(&Vt[d * 64 + swz * 8]);
        acc[fc] = __builtin_amdgcn_mfma_f32_16x16x32_bf16(pa[kc], bv, acc[fc], 0, 0, 0);
      }
    }
  }

  const int b = bh >> 4, h = bh & 15;
#pragma unroll
  for (int fc = 0; fc < 4; ++fc) {
#pragma unroll
    for (int r = 0; r < 4; ++r) {
      int srow = q0 + lg * 4 + r;
      float o = acc[fc][r] / lsum[r];
      AO[((size_t)(b * SEQ + srow)) * HIDDEN + h * HDIM + fc * 16 + lr] = tobf(o);
    }
  }
}

// ---------------- launch ----------------
extern "C" void kernel_launch(void* const* d_in, const int* in_sizes, int n_in,
                              void* d_out, int out_size, void* d_ws, size_t ws_size,
                              hipStream_t stream) {
  const float* x  = (const float*)d_in[0];
  const float* Wq = (const float*)d_in[1];
  const float* bq = (const float*)d_in[2];
  const float* Wk = (const float*)d_in[3];
  const float* bk = (const float*)d_in[4];
  const float* Wv = (const float*)d_in[5];
  const float* bv = (const float*)d_in[6];
  const float* Wo = (const float*)d_in[7];
  const float* bo = (const float*)d_in[8];

  char* ws = (char*)d_ws;
  const size_t XB = (size_t)M_TOK * HIDDEN * 2;   // 8 MB (token-major bf16)
  const size_t WB = (size_t)HIDDEN * HIDDEN * 2;  // 2 MB per weight
  bf16_t* xb  = (bf16_t*)(ws);
  bf16_t* Wqb = (bf16_t*)(ws + XB);
  bf16_t* Wkb = (bf16_t*)(ws + XB + 1 * WB);
  bf16_t* Wvb = (bf16_t*)(ws + XB + 2 * WB);
  bf16_t* Wob = (bf16_t*)(ws + XB + 3 * WB);
  bf16_t* Qb  = (bf16_t*)(ws + XB + 4 * WB);
  bf16_t* Kb  = (bf16_t*)(ws + 2 * XB + 4 * WB);
  bf16_t* Vb  = (bf16_t*)(ws + 3 * XB + 4 * WB);
  bf16_t* AOb = (bf16_t*)(ws + 4 * XB + 4 * WB);  // total 48 MB

  k_convert<<<(M_TOK * HIDDEN) / 1024, 256, 0, stream>>>(x, xb, M_TOK * HIDDEN);
  k_convert<<<(HIDDEN * HIDDEN) / 1024, 256, 0, stream>>>(Wq, Wqb, HIDDEN * HIDDEN);
  k_convert<<<(HIDDEN * HIDDEN) / 1024, 256, 0, stream>>>(Wk, Wkb, HIDDEN * HIDDEN);
  k_convert<<<(HIDDEN * HIDDEN) / 1024, 256, 0, stream>>>(Wv, Wvb, HIDDEN * HIDDEN);
  k_convert<<<(HIDDEN * HIDDEN) / 1024, 256, 0, stream>>>(Wo, Wob, HIDDEN * HIDDEN);

  dim3 gg(M_TOK / 128, HIDDEN / 128);  // 32 x 8
  k_gemm_bt<0><<<gg, 256, 0, stream>>>(xb, Wqb, bq, Qb);
  k_gemm_bt<0><<<gg, 256, 0, stream>>>(xb, Wkb, bk, Kb);
  k_gemm_bt<0><<<gg, 256, 0, stream>>>(xb, Wvb, bv, Vb);

  k_attn<<<dim3(SEQ / 64, BATCH * HEADS), 256, 0, stream>>>(Qb, Kb, Vb, AOb);

  k_gemm_bt<1><<<gg, 256, 0, stream>>>(AOb, Wob, bo, d_out);
}

// Round 7
// 231.455 us; speedup vs baseline: 1.1659x; 1.1659x over previous
//
#include <hip/hip_runtime.h>
#include <hip/hip_bf16.h>
#include <stdint.h>

#define HIDDEN 1024
#define SEQ 2048
#define BATCH 2
#define HEADS 16
#define HDIM 64
#define M_TOK (BATCH * SEQ)  // 4096

using bf16_t = __bf16;
typedef __attribute__((ext_vector_type(8))) __bf16 bf16x8;
typedef __attribute__((ext_vector_type(4))) float f32x4;

__device__ __forceinline__ bf16_t tobf(float f) {
  uint32_t u = __builtin_bit_cast(uint32_t, f);
  u += 0x7FFFu + ((u >> 16) & 1u);  // round-to-nearest-even
  uint16_t h = (uint16_t)(u >> 16);
  return __builtin_bit_cast(bf16_t, h);
}

__device__ __forceinline__ void async_cp16(const bf16_t* g, bf16_t* l) {
  __builtin_amdgcn_global_load_lds(
      (const __attribute__((address_space(1))) uint32_t*)g,
      (__attribute__((address_space(3))) uint32_t*)l, 16, 0, 0);
}

// ---------------- fp32 -> bf16 convert (single tensor) ----------------
__global__ __launch_bounds__(256) void k_convert(const float* __restrict__ src,
                                                 bf16_t* __restrict__ dst, int n) {
  int i = (blockIdx.x * 256 + threadIdx.x) * 4;
  if (i >= n) return;
  float4 v = *(const float4*)(src + i);
  union { bf16_t b[4]; uint64_t u; } o;
  o.b[0] = tobf(v.x); o.b[1] = tobf(v.y); o.b[2] = tobf(v.z); o.b[3] = tobf(v.w);
  *(uint64_t*)(dst + i) = o.u;
}

// ---------------- fp32 -> bf16 convert, 4 weight matrices in one launch ----
__global__ __launch_bounds__(256) void k_convert4(
    const float* __restrict__ s0, const float* __restrict__ s1,
    const float* __restrict__ s2, const float* __restrict__ s3,
    bf16_t* __restrict__ d0, bf16_t* __restrict__ d1,
    bf16_t* __restrict__ d2, bf16_t* __restrict__ d3) {
  const int wsel = blockIdx.y;
  const float* src = (wsel == 0) ? s0 : (wsel == 1) ? s1 : (wsel == 2) ? s2 : s3;
  bf16_t* dst = (wsel == 0) ? d0 : (wsel == 1) ? d1 : (wsel == 2) ? d2 : d3;
  int i = (blockIdx.x * 256 + threadIdx.x) * 4;
  float4 v = *(const float4*)(src + i);
  union { bf16_t b[4]; uint64_t u; } o;
  o.b[0] = tobf(v.x); o.b[1] = tobf(v.y); o.b[2] = tobf(v.z); o.b[3] = tobf(v.w);
  *(uint64_t*)(dst + i) = o.u;
}

// ---------------- GEMM core: C[m,n] = sum_k A[m,k] * Bw[n,k] + bias[n] -------
// MODE 0: bf16 out scattered to [B][H][S][D]   MODE 1: f32 out linear [M][N]
template <int MODE>
__device__ __forceinline__ void gemm_bt_body(const bf16_t* __restrict__ A,
                                             const bf16_t* __restrict__ Bw,
                                             const float* __restrict__ bias,
                                             void* __restrict__ dst,
                                             bf16_t* As, bf16_t* Bs) {
  constexpr int K = HIDDEN;
  const int tid = threadIdx.x;
  const int lane = tid & 63;
  const int w = tid >> 6;
  const int wr = w >> 1, wc = w & 1;
  const int lr = lane & 15, lg = lane >> 4;
  const int m0 = blockIdx.x * 128;
  const int n0 = blockIdx.y * 128;

  f32x4 acc[4][4];
#pragma unroll
  for (int i = 0; i < 4; ++i)
#pragma unroll
    for (int j = 0; j < 4; ++j) acc[i][j] = f32x4{0.f, 0.f, 0.f, 0.f};

  for (int k0 = 0; k0 < K; k0 += 32) {
#pragma unroll
    for (int i = 0; i < 2; ++i) {
      int c = w * 128 + i * 64 + lane;  // 0..511, 16B chunk id
      int row = c >> 2, kc = c & 3;
      async_cp16(A + (size_t)(m0 + row) * K + k0 + kc * 8, As + c * 8);
      async_cp16(Bw + (size_t)(n0 + row) * K + k0 + kc * 8, Bs + c * 8);
    }
    __syncthreads();
    bf16x8 af[4], bfr[4];
#pragma unroll
    for (int mi = 0; mi < 4; ++mi)
      af[mi] = *(const bf16x8*)(As + (wr * 64 + mi * 16 + lr) * 32 + lg * 8);
#pragma unroll
    for (int ni = 0; ni < 4; ++ni)
      bfr[ni] = *(const bf16x8*)(Bs + (wc * 64 + ni * 16 + lr) * 32 + lg * 8);
#pragma unroll
    for (int mi = 0; mi < 4; ++mi)
#pragma unroll
      for (int ni = 0; ni < 4; ++ni)
        acc[mi][ni] = __builtin_amdgcn_mfma_f32_16x16x32_bf16(af[mi], bfr[ni], acc[mi][ni], 0, 0, 0);
    __syncthreads();
  }

#pragma unroll
  for (int ni = 0; ni < 4; ++ni) {
    int col = n0 + wc * 64 + ni * 16 + lr;
    float bv = bias[col];
#pragma unroll
    for (int mi = 0; mi < 4; ++mi) {
#pragma unroll
      for (int r = 0; r < 4; ++r) {
        int m = m0 + wr * 64 + mi * 16 + lg * 4 + r;
        float v = acc[mi][ni][r] + bv;
        if (MODE == 0) {
          int b = m >> 11, s = m & (SEQ - 1);
          int h = col >> 6, d = col & 63;
          ((bf16_t*)dst)[(((size_t)(b * HEADS + h) * SEQ) + s) * HDIM + d] = tobf(v);
        } else {
          ((float*)dst)[(size_t)m * HIDDEN + col] = v;
        }
      }
    }
  }
}

// fused QKV: blockIdx.z selects {Wq,bq,Qb} / {Wk,bk,Kb} / {Wv,bv,Vb}
__global__ __launch_bounds__(256) void k_gemm_qkv(
    const bf16_t* __restrict__ A,
    const bf16_t* __restrict__ Wqb, const bf16_t* __restrict__ Wkb,
    const bf16_t* __restrict__ Wvb,
    const float* __restrict__ bq, const float* __restrict__ bk,
    const float* __restrict__ bv,
    bf16_t* __restrict__ Qb, bf16_t* __restrict__ Kb, bf16_t* __restrict__ Vb) {
  __shared__ bf16_t As[128 * 32];
  __shared__ bf16_t Bs[128 * 32];
  const int z = blockIdx.z;
  const bf16_t* Bw = (z == 0) ? Wqb : (z == 1) ? Wkb : Wvb;
  const float* bias = (z == 0) ? bq : (z == 1) ? bk : bv;
  bf16_t* dst = (z == 0) ? Qb : (z == 1) ? Kb : Vb;
  gemm_bt_body<0>(A, Bw, bias, dst, As, Bs);
}

__global__ __launch_bounds__(256) void k_gemm_out(const bf16_t* __restrict__ A,
                                                  const bf16_t* __restrict__ Bw,
                                                  const float* __restrict__ bias,
                                                  float* __restrict__ dst) {
  __shared__ bf16_t As[128 * 32];
  __shared__ bf16_t Bs[128 * 32];
  gemm_bt_body<1>(A, Bw, bias, dst, As, Bs);
}

// ---------------- flash attention (R1-verified version, verbatim) ----------
// grid: (SEQ/64, BATCH*HEADS), block 256. Wave w handles q-rows [q0, q0+16).
__global__ __launch_bounds__(256) void k_attn(const bf16_t* __restrict__ Q,
                                              const bf16_t* __restrict__ Kk,
                                              const bf16_t* __restrict__ V,
                                              bf16_t* __restrict__ AO) {
  __shared__ bf16_t Vt[64 * 64];      // transposed V tile [d][k], XOR-swizzled
  __shared__ bf16_t Pl[4][16 * 64];   // per-wave P tile, XOR-swizzled
  const int tid = threadIdx.x;
  const int lane = tid & 63;
  const int w = tid >> 6;
  const int lr = lane & 15, lg = lane >> 4;
  const int bh = blockIdx.y;
  const int q0 = blockIdx.x * 64 + w * 16;
  const bf16_t* Qh = Q + (size_t)bh * SEQ * HDIM;
  const bf16_t* Kh = Kk + (size_t)bh * SEQ * HDIM;
  const bf16_t* Vh = V + (size_t)bh * SEQ * HDIM;

  // Q fragments, scale folded in (1/sqrt(64) * log2(e) so we can use exp2)
  const float qscale = 0.125f * 1.44269504088896f;
  bf16x8 aq[2];
#pragma unroll
  for (int dc = 0; dc < 2; ++dc) {
    bf16x8 t = *(const bf16x8*)(Qh + (size_t)(q0 + lr) * HDIM + dc * 32 + lg * 8);
#pragma unroll
    for (int j = 0; j < 8; ++j) t[j] = tobf((float)t[j] * qscale);
    aq[dc] = t;
  }

  float mrow[4], lsum[4];
  f32x4 acc[4];
#pragma unroll
  for (int r = 0; r < 4; ++r) { mrow[r] = -1e30f; lsum[r] = 0.f; }
#pragma unroll
  for (int fc = 0; fc < 4; ++fc) acc[fc] = f32x4{0.f, 0.f, 0.f, 0.f};

  for (int kt = 0; kt < SEQ / 64; ++kt) {
    const int kr0 = kt * 64;
    __syncthreads();  // protect Vt from overwrite while still being read
    {   // stage V tile transposed + swizzled: thread -> (k = tid>>2, d0 = (tid&3)*16)
      int k = tid >> 2, d0 = (tid & 3) * 16;
      const bf16_t* vp = Vh + (size_t)(kr0 + k) * HDIM + d0;
#pragma unroll
      for (int half = 0; half < 2; ++half) {
        bf16x8 vv = *(const bf16x8*)(vp + half * 8);
#pragma unroll
        for (int j = 0; j < 8; ++j) {
          int d = d0 + half * 8 + j;
          Vt[d * 64 + (((k >> 3) ^ (d & 7)) * 8) + (k & 7)] = vv[j];
        }
      }
    }
    __syncthreads();

    // S = Q @ K^T  (K fragments straight from global; tile is L2-resident)
    f32x4 sf[4];
#pragma unroll
    for (int fc = 0; fc < 4; ++fc) {
      f32x4 a = f32x4{0.f, 0.f, 0.f, 0.f};
      int kr = kr0 + fc * 16 + lr;
#pragma unroll
      for (int dc = 0; dc < 2; ++dc) {
        bf16x8 bk = *(const bf16x8*)(Kh + (size_t)kr * HDIM + dc * 32 + lg * 8);
        a = __builtin_amdgcn_mfma_f32_16x16x32_bf16(aq[dc], bk, a, 0, 0, 0);
      }
      sf[fc] = a;
    }

    // online softmax (exp2 domain); lane owns rows lg*4+r, cols fc*16+lr
    float pv[4][4];
#pragma unroll
    for (int r = 0; r < 4; ++r) {
      float mx = fmaxf(fmaxf(sf[0][r], sf[1][r]), fmaxf(sf[2][r], sf[3][r]));
      mx = fmaxf(mx, __shfl_xor(mx, 1));
      mx = fmaxf(mx, __shfl_xor(mx, 2));
      mx = fmaxf(mx, __shfl_xor(mx, 4));
      mx = fmaxf(mx, __shfl_xor(mx, 8));
      float mn = fmaxf(mrow[r], mx);
      float sc = exp2f(mrow[r] - mn);
      mrow[r] = mn;
      float ts = 0.f;
#pragma unroll
      for (int fc = 0; fc < 4; ++fc) {
        float p = exp2f(sf[fc][r] - mn);
        pv[fc][r] = p;
        ts += p;
      }
      ts += __shfl_xor(ts, 1);
      ts += __shfl_xor(ts, 2);
      ts += __shfl_xor(ts, 4);
      ts += __shfl_xor(ts, 8);
      lsum[r] = lsum[r] * sc + ts;
#pragma unroll
      for (int fc = 0; fc < 4; ++fc) acc[fc][r] = acc[fc][r] * sc;
    }

    // P -> LDS (swizzled), wave-private
#pragma unroll
    for (int fc = 0; fc < 4; ++fc) {
      int col = fc * 16 + lr;
#pragma unroll
      for (int r = 0; r < 4; ++r) {
        int row = lg * 4 + r;
        Pl[w][row * 64 + (((col >> 3) ^ (row & 7)) * 8) + (col & 7)] = tobf(pv[fc][r]);
      }
    }

    // P A-fragments back from LDS
    bf16x8 pa[2];
#pragma unroll
    for (int kc = 0; kc < 2; ++kc) {
      int swz = (kc * 4 + lg) ^ (lr & 7);
      pa[kc] = *(const bf16x8*)(&Pl[w][lr * 64 + swz * 8]);
    }
    // O += P @ V
#pragma unroll
    for (int fc = 0; fc < 4; ++fc) {
      int d = fc * 16 + lr;
#pragma unroll
      for (int kc = 0; kc < 2; ++kc) {
        int swz = (kc * 4 + lg) ^ (d & 7);
        bf16x8 bv = *(const bf16x8*)(&Vt[d * 64 + swz * 8]);
        acc[fc] = __builtin_amdgcn_mfma_f32_16x16x32_bf16(pa[kc], bv, acc[fc], 0, 0, 0);
      }
    }
  }

  const int b = bh >> 4, h = bh & 15;
#pragma unroll
  for (int fc = 0; fc < 4; ++fc) {
#pragma unroll
    for (int r = 0; r < 4; ++r) {
      int srow = q0 + lg * 4 + r;
      float o = acc[fc][r] / lsum[r];
      AO[((size_t)(b * SEQ + srow)) * HIDDEN + h * HDIM + fc * 16 + lr] = tobf(o);
    }
  }
}

// ---------------- launch ----------------
extern "C" void kernel_launch(void* const* d_in, const int* in_sizes, int n_in,
                              void* d_out, int out_size, void* d_ws, size_t ws_size,
                              hipStream_t stream) {
  const float* x  = (const float*)d_in[0];
  const float* Wq = (const float*)d_in[1];
  const float* bq = (const float*)d_in[2];
  const float* Wk = (const float*)d_in[3];
  const float* bk = (const float*)d_in[4];
  const float* Wv = (const float*)d_in[5];
  const float* bv = (const float*)d_in[6];
  const float* Wo = (const float*)d_in[7];
  const float* bo = (const float*)d_in[8];

  char* ws = (char*)d_ws;
  const size_t XB = (size_t)M_TOK * HIDDEN * 2;   // 8 MB (token-major bf16)
  const size_t WB = (size_t)HIDDEN * HIDDEN * 2;  // 2 MB per weight
  bf16_t* xb  = (bf16_t*)(ws);
  bf16_t* Wqb = (bf16_t*)(ws + XB);
  bf16_t* Wkb = (bf16_t*)(ws + XB + 1 * WB);
  bf16_t* Wvb = (bf16_t*)(ws + XB + 2 * WB);
  bf16_t* Wob = (bf16_t*)(ws + XB + 3 * WB);
  bf16_t* Qb  = (bf16_t*)(ws + XB + 4 * WB);
  bf16_t* Kb  = (bf16_t*)(ws + 2 * XB + 4 * WB);
  bf16_t* Vb  = (bf16_t*)(ws + 3 * XB + 4 * WB);
  bf16_t* AOb = (bf16_t*)(ws + 4 * XB + 4 * WB);  // total 48 MB

  k_convert<<<(M_TOK * HIDDEN) / 1024, 256, 0, stream>>>(x, xb, M_TOK * HIDDEN);
  k_convert4<<<dim3((HIDDEN * HIDDEN) / 1024, 4), 256, 0, stream>>>(
      Wq, Wk, Wv, Wo, Wqb, Wkb, Wvb, Wob);

  dim3 gg(M_TOK / 128, HIDDEN / 128);  // 32 x 8
  k_gemm_qkv<<<dim3(M_TOK / 128, HIDDEN / 128, 3), 256, 0, stream>>>(
      xb, Wqb, Wkb, Wvb, bq, bk, bv, Qb, Kb, Vb);

  k_attn<<<dim3(SEQ / 64, BATCH * HEADS), 256, 0, stream>>>(Qb, Kb, Vb, AOb);

  k_gemm_out<<<gg, 256, 0, stream>>>(AOb, Wob, bo, (float*)d_out);
}

// Round 9
// 196.103 us; speedup vs baseline: 1.3761x; 1.1803x over previous
//
#include <hip/hip_runtime.h>
#include <hip/hip_bf16.h>
#include <stdint.h>

#define HIDDEN 1024
#define SEQ 2048
#define BATCH 2
#define HEADS 16
#define HDIM 64
#define M_TOK (BATCH * SEQ)  // 4096

using bf16_t = __bf16;
typedef __attribute__((ext_vector_type(8))) __bf16 bf16x8;
typedef __attribute__((ext_vector_type(4))) float f32x4;

__device__ __forceinline__ bf16_t tobf(float f) {
  uint32_t u = __builtin_bit_cast(uint32_t, f);
  u += 0x7FFFu + ((u >> 16) & 1u);  // round-to-nearest-even
  uint16_t h = (uint16_t)(u >> 16);
  return __builtin_bit_cast(bf16_t, h);
}

__device__ __forceinline__ void async_cp16(const bf16_t* g, bf16_t* l) {
  __builtin_amdgcn_global_load_lds(
      (const __attribute__((address_space(1))) uint32_t*)g,
      (__attribute__((address_space(3))) uint32_t*)l, 16, 0, 0);
}

// ---------------- fp32 -> bf16 convert (single tensor) ----------------
__global__ __launch_bounds__(256) void k_convert(const float* __restrict__ src,
                                                 bf16_t* __restrict__ dst, int n) {
  int i = (blockIdx.x * 256 + threadIdx.x) * 4;
  if (i >= n) return;
  float4 v = *(const float4*)(src + i);
  union { bf16_t b[4]; uint64_t u; } o;
  o.b[0] = tobf(v.x); o.b[1] = tobf(v.y); o.b[2] = tobf(v.z); o.b[3] = tobf(v.w);
  *(uint64_t*)(dst + i) = o.u;
}

// ---------------- fp32 -> bf16 convert, 4 weight matrices in one launch ----
__global__ __launch_bounds__(256) void k_convert4(
    const float* __restrict__ s0, const float* __restrict__ s1,
    const float* __restrict__ s2, const float* __restrict__ s3,
    bf16_t* __restrict__ d0, bf16_t* __restrict__ d1,
    bf16_t* __restrict__ d2, bf16_t* __restrict__ d3) {
  const int wsel = blockIdx.y;
  const float* src = (wsel == 0) ? s0 : (wsel == 1) ? s1 : (wsel == 2) ? s2 : s3;
  bf16_t* dst = (wsel == 0) ? d0 : (wsel == 1) ? d1 : (wsel == 2) ? d2 : d3;
  int i = (blockIdx.x * 256 + threadIdx.x) * 4;
  float4 v = *(const float4*)(src + i);
  union { bf16_t b[4]; uint64_t u; } o;
  o.b[0] = tobf(v.x); o.b[1] = tobf(v.y); o.b[2] = tobf(v.z); o.b[3] = tobf(v.w);
  *(uint64_t*)(dst + i) = o.u;
}

// ---------------- GEMM core: C[m,n] = sum_k A[m,k] * Bw[n,k] + bias[n] -------
// MODE 0: bf16 out scattered to [B][H][S][D]   MODE 1: f32 out linear [M][N]
template <int MODE>
__device__ __forceinline__ void gemm_bt_body(const bf16_t* __restrict__ A,
                                             const bf16_t* __restrict__ Bw,
                                             const float* __restrict__ bias,
                                             void* __restrict__ dst,
                                             bf16_t* As, bf16_t* Bs) {
  constexpr int K = HIDDEN;
  const int tid = threadIdx.x;
  const int lane = tid & 63;
  const int w = tid >> 6;
  const int wr = w >> 1, wc = w & 1;
  const int lr = lane & 15, lg = lane >> 4;
  const int m0 = blockIdx.x * 128;
  const int n0 = blockIdx.y * 128;

  f32x4 acc[4][4];
#pragma unroll
  for (int i = 0; i < 4; ++i)
#pragma unroll
    for (int j = 0; j < 4; ++j) acc[i][j] = f32x4{0.f, 0.f, 0.f, 0.f};

  for (int k0 = 0; k0 < K; k0 += 32) {
#pragma unroll
    for (int i = 0; i < 2; ++i) {
      int c = w * 128 + i * 64 + lane;  // 0..511, 16B chunk id
      int row = c >> 2, kc = c & 3;
      async_cp16(A + (size_t)(m0 + row) * K + k0 + kc * 8, As + c * 8);
      async_cp16(Bw + (size_t)(n0 + row) * K + k0 + kc * 8, Bs + c * 8);
    }
    __syncthreads();
    bf16x8 af[4], bfr[4];
#pragma unroll
    for (int mi = 0; mi < 4; ++mi)
      af[mi] = *(const bf16x8*)(As + (wr * 64 + mi * 16 + lr) * 32 + lg * 8);
#pragma unroll
    for (int ni = 0; ni < 4; ++ni)
      bfr[ni] = *(const bf16x8*)(Bs + (wc * 64 + ni * 16 + lr) * 32 + lg * 8);
#pragma unroll
    for (int mi = 0; mi < 4; ++mi)
#pragma unroll
      for (int ni = 0; ni < 4; ++ni)
        acc[mi][ni] = __builtin_amdgcn_mfma_f32_16x16x32_bf16(af[mi], bfr[ni], acc[mi][ni], 0, 0, 0);
    __syncthreads();
  }

#pragma unroll
  for (int ni = 0; ni < 4; ++ni) {
    int col = n0 + wc * 64 + ni * 16 + lr;
    float bv = bias[col];
#pragma unroll
    for (int mi = 0; mi < 4; ++mi) {
#pragma unroll
      for (int r = 0; r < 4; ++r) {
        int m = m0 + wr * 64 + mi * 16 + lg * 4 + r;
        float v = acc[mi][ni][r] + bv;
        if (MODE == 0) {
          int b = m >> 11, s = m & (SEQ - 1);
          int h = col >> 6, d = col & 63;
          ((bf16_t*)dst)[(((size_t)(b * HEADS + h) * SEQ) + s) * HDIM + d] = tobf(v);
        } else {
          ((float*)dst)[(size_t)m * HIDDEN + col] = v;
        }
      }
    }
  }
}

// fused QKV: blockIdx.z selects {Wq,bq,Qb} / {Wk,bk,Kb} / {Wv,bv,Vb}
__global__ __launch_bounds__(256) void k_gemm_qkv(
    const bf16_t* __restrict__ A,
    const bf16_t* __restrict__ Wqb, const bf16_t* __restrict__ Wkb,
    const bf16_t* __restrict__ Wvb,
    const float* __restrict__ bq, const float* __restrict__ bk,
    const float* __restrict__ bv,
    bf16_t* __restrict__ Qb, bf16_t* __restrict__ Kb, bf16_t* __restrict__ Vb) {
  __shared__ bf16_t As[128 * 32];
  __shared__ bf16_t Bs[128 * 32];
  const int z = blockIdx.z;
  const bf16_t* Bw = (z == 0) ? Wqb : (z == 1) ? Wkb : Wvb;
  const float* bias = (z == 0) ? bq : (z == 1) ? bk : bv;
  bf16_t* dst = (z == 0) ? Qb : (z == 1) ? Kb : Vb;
  gemm_bt_body<0>(A, Bw, bias, dst, As, Bs);
}

__global__ __launch_bounds__(256) void k_gemm_out(const bf16_t* __restrict__ A,
                                                  const bf16_t* __restrict__ Bw,
                                                  const float* __restrict__ bias,
                                                  float* __restrict__ dst) {
  __shared__ bf16_t As[128 * 32];
  __shared__ bf16_t Bs[128 * 32];
  gemm_bt_body<1>(A, Bw, bias, dst, As, Bs);
}

// ---------------- flash attention: R8 minus packed-V-staging ----------------
// grid: (SEQ/64, BATCH*HEADS), block 256. Wave w handles q-rows [q0, q0+16).
// vs R7-green, keeps: (A) denominator via ones-column MFMA, (B) defer-max
// with lane-local pretest, (D) setprio around MFMA clusters.
// REVERTED: V staging is R1's verbatim scalar transpose (the packed-u32
// staging is the one change common to ALL failing rounds R3-R6,R8).
__global__ __launch_bounds__(256) void k_attn(const bf16_t* __restrict__ Q,
                                              const bf16_t* __restrict__ Kk,
                                              const bf16_t* __restrict__ V,
                                              bf16_t* __restrict__ AO) {
  __shared__ bf16_t Vt[64 * 64];      // transposed V tile [d][k], XOR-swizzled
  __shared__ bf16_t Pl[4][16 * 64];   // per-wave P tile, XOR-swizzled
  const int tid = threadIdx.x;
  const int lane = tid & 63;
  const int w = tid >> 6;
  const int lr = lane & 15, lg = lane >> 4;
  const int bh = blockIdx.y;
  const int q0 = blockIdx.x * 64 + w * 16;
  const bf16_t* Qh = Q + (size_t)bh * SEQ * HDIM;
  const bf16_t* Kh = Kk + (size_t)bh * SEQ * HDIM;
  const bf16_t* Vh = V + (size_t)bh * SEQ * HDIM;

  // Q fragments, scale folded in (1/sqrt(64) * log2(e) so we can use exp2)
  const float qscale = 0.125f * 1.44269504088896f;
  bf16x8 aq[2];
#pragma unroll
  for (int dc = 0; dc < 2; ++dc) {
    bf16x8 t = *(const bf16x8*)(Qh + (size_t)(q0 + lr) * HDIM + dc * 32 + lg * 8);
#pragma unroll
    for (int j = 0; j < 8; ++j) t[j] = tobf((float)t[j] * qscale);
    aq[dc] = t;
  }

  // ones B-fragment: D = P . ones => every D column = row-sum of P
  bf16x8 vone;
#pragma unroll
  for (int j = 0; j < 8; ++j) vone[j] = tobf(1.0f);

  float mrow[4];
  f32x4 acc[4];
  f32x4 accd = f32x4{0.f, 0.f, 0.f, 0.f};  // softmax denominator per row
#pragma unroll
  for (int r = 0; r < 4; ++r) mrow[r] = -1e30f;
#pragma unroll
  for (int fc = 0; fc < 4; ++fc) acc[fc] = f32x4{0.f, 0.f, 0.f, 0.f};

  for (int kt = 0; kt < SEQ / 64; ++kt) {
    const int kr0 = kt * 64;
    __syncthreads();  // protect Vt from overwrite while still being read
    {   // stage V tile transposed + swizzled (VERBATIM R1):
        // thread -> (k = tid>>2, d0 = (tid&3)*16)
      int k = tid >> 2, d0 = (tid & 3) * 16;
      const bf16_t* vp = Vh + (size_t)(kr0 + k) * HDIM + d0;
#pragma unroll
      for (int half = 0; half < 2; ++half) {
        bf16x8 vv = *(const bf16x8*)(vp + half * 8);
#pragma unroll
        for (int j = 0; j < 8; ++j) {
          int d = d0 + half * 8 + j;
          Vt[d * 64 + (((k >> 3) ^ (d & 7)) * 8) + (k & 7)] = vv[j];
        }
      }
    }
    __syncthreads();

    // S = Q @ K^T  (K fragments straight from global; tile is L2-resident)
    f32x4 sf[4];
    __builtin_amdgcn_s_setprio(1);
#pragma unroll
    for (int fc = 0; fc < 4; ++fc) {
      f32x4 a = f32x4{0.f, 0.f, 0.f, 0.f};
      int kr = kr0 + fc * 16 + lr;
#pragma unroll
      for (int dc = 0; dc < 2; ++dc) {
        bf16x8 bk = *(const bf16x8*)(Kh + (size_t)kr * HDIM + dc * 32 + lg * 8);
        a = __builtin_amdgcn_mfma_f32_16x16x32_bf16(aq[dc], bk, a, 0, 0, 0);
      }
      sf[fc] = a;
    }
    __builtin_amdgcn_s_setprio(0);

    // defer-max (T13): lane-local pretest; full reduce+rescale only on growth
    float pmax[4];
#pragma unroll
    for (int r = 0; r < 4; ++r)
      pmax[r] = fmaxf(fmaxf(sf[0][r], sf[1][r]), fmaxf(sf[2][r], sf[3][r]));
    int ok = (pmax[0] <= mrow[0] + 8.f) && (pmax[1] <= mrow[1] + 8.f) &&
             (pmax[2] <= mrow[2] + 8.f) && (pmax[3] <= mrow[3] + 8.f);
    if (!__all(ok)) {
#pragma unroll
      for (int r = 0; r < 4; ++r) {
        float mx = pmax[r];
        mx = fmaxf(mx, __shfl_xor(mx, 1));
        mx = fmaxf(mx, __shfl_xor(mx, 2));
        mx = fmaxf(mx, __shfl_xor(mx, 4));
        mx = fmaxf(mx, __shfl_xor(mx, 8));
        float mn = fmaxf(mrow[r], mx);
        float sc = exp2f(mrow[r] - mn);
        mrow[r] = mn;
        accd[r] *= sc;
#pragma unroll
        for (int fc = 0; fc < 4; ++fc) acc[fc][r] *= sc;
      }
    }
    // P values (bounded by 2^8 under defer-max)
    float pv[4][4];
#pragma unroll
    for (int r = 0; r < 4; ++r)
#pragma unroll
      for (int fc = 0; fc < 4; ++fc) pv[fc][r] = exp2f(sf[fc][r] - mrow[r]);

    // P -> LDS (swizzled), wave-private  [verbatim R1]
#pragma unroll
    for (int fc = 0; fc < 4; ++fc) {
      int col = fc * 16 + lr;
#pragma unroll
      for (int r = 0; r < 4; ++r) {
        int row = lg * 4 + r;
        Pl[w][row * 64 + (((col >> 3) ^ (row & 7)) * 8) + (col & 7)] = tobf(pv[fc][r]);
      }
    }

    // P A-fragments back from LDS  [verbatim R1]
    bf16x8 pa[2];
#pragma unroll
    for (int kc = 0; kc < 2; ++kc) {
      int swz = (kc * 4 + lg) ^ (lr & 7);
      pa[kc] = *(const bf16x8*)(&Pl[w][lr * 64 + swz * 8]);
    }
    // O += P @ V ; denominator += P . ones
    __builtin_amdgcn_s_setprio(1);
#pragma unroll
    for (int fc = 0; fc < 4; ++fc) {
      int d = fc * 16 + lr;
#pragma unroll
      for (int kc = 0; kc < 2; ++kc) {
        int swz = (kc * 4 + lg) ^ (d & 7);
        bf16x8 bv = *(const bf16x8*)(&Vt[d * 64 + swz * 8]);
        acc[fc] = __builtin_amdgcn_mfma_f32_16x16x32_bf16(pa[kc], bv, acc[fc], 0, 0, 0);
      }
    }
    accd = __builtin_amdgcn_mfma_f32_16x16x32_bf16(pa[0], vone, accd, 0, 0, 0);
    accd = __builtin_amdgcn_mfma_f32_16x16x32_bf16(pa[1], vone, accd, 0, 0, 0);
    __builtin_amdgcn_s_setprio(0);
  }

  const int b = bh >> 4, h = bh & 15;
#pragma unroll
  for (int fc = 0; fc < 4; ++fc) {
#pragma unroll
    for (int r = 0; r < 4; ++r) {
      int srow = q0 + lg * 4 + r;
      float o = acc[fc][r] / accd[r];
      AO[((size_t)(b * SEQ + srow)) * HIDDEN + h * HDIM + fc * 16 + lr] = tobf(o);
    }
  }
}

// ---------------- launch ----------------
extern "C" void kernel_launch(void* const* d_in, const int* in_sizes, int n_in,
                              void* d_out, int out_size, void* d_ws, size_t ws_size,
                              hipStream_t stream) {
  const float* x  = (const float*)d_in[0];
  const float* Wq = (const float*)d_in[1];
  const float* bq = (const float*)d_in[2];
  const float* Wk = (const float*)d_in[3];
  const float* bk = (const float*)d_in[4];
  const float* Wv = (const float*)d_in[5];
  const float* bv = (const float*)d_in[6];
  const float* Wo = (const float*)d_in[7];
  const float* bo = (const float*)d_in[8];

  char* ws = (char*)d_ws;
  const size_t XB = (size_t)M_TOK * HIDDEN * 2;   // 8 MB (token-major bf16)
  const size_t WB = (size_t)HIDDEN * HIDDEN * 2;  // 2 MB per weight
  bf16_t* xb  = (bf16_t*)(ws);
  bf16_t* Wqb = (bf16_t*)(ws + XB);
  bf16_t* Wkb = (bf16_t*)(ws + XB + 1 * WB);
  bf16_t* Wvb = (bf16_t*)(ws + XB + 2 * WB);
  bf16_t* Wob = (bf16_t*)(ws + XB + 3 * WB);
  bf16_t* Qb  = (bf16_t*)(ws + XB + 4 * WB);
  bf16_t* Kb  = (bf16_t*)(ws + 2 * XB + 4 * WB);
  bf16_t* Vb  = (bf16_t*)(ws + 3 * XB + 4 * WB);
  bf16_t* AOb = (bf16_t*)(ws + 4 * XB + 4 * WB);  // total 48 MB

  k_convert<<<(M_TOK * HIDDEN) / 1024, 256, 0, stream>>>(x, xb, M_TOK * HIDDEN);
  k_convert4<<<dim3((HIDDEN * HIDDEN) / 1024, 4), 256, 0, stream>>>(
      Wq, Wk, Wv, Wo, Wqb, Wkb, Wvb, Wob);

  dim3 gg(M_TOK / 128, HIDDEN / 128);  // 32 x 8
  k_gemm_qkv<<<dim3(M_TOK / 128, HIDDEN / 128, 3), 256, 0, stream>>>(
      xb, Wqb, Wkb, Wvb, bq, bk, bv, Qb, Kb, Vb);

  k_attn<<<dim3(SEQ / 64, BATCH * HEADS), 256, 0, stream>>>(Qb, Kb, Vb, AOb);

  k_gemm_out<<<gg, 256, 0, stream>>>(AOb, Wob, bo, (float*)d_out);
}